// Round 1
// baseline (342.198 us; speedup 1.0000x reference)
//
#include <hip/hip_runtime.h>
#include <cmath>

// ---------------------------------------------------------------------------
// 2-layer GAT: N=10000 nodes, E=160000 edges (+self loops), F_IN=256,
// L1: heads=8, C=128 (concat -> 1024) + ELU; L2: heads=1, C=64.
// All fp32. CSR built on device each call (deterministic up to fp add order).
// ---------------------------------------------------------------------------

__device__ __forceinline__ float lrelu(float x) { return x > 0.f ? x : 0.2f * x; }

// ---- CSR build ------------------------------------------------------------

__global__ __launch_bounds__(256) void count_kernel(const int* __restrict__ ei,
                                                    int* __restrict__ counts, int E) {
  int e = blockIdx.x * 256 + threadIdx.x;
  if (e < E) atomicAdd(&counts[ei[E + e]], 1);
}

__global__ __launch_bounds__(1024) void scan_kernel(const int* __restrict__ counts,
                                                    int* __restrict__ offsets,
                                                    int* __restrict__ cursors, int n) {
  __shared__ int lds[1024];
  __shared__ int carry;
  if (threadIdx.x == 0) carry = 0;
  __syncthreads();
  for (int base = 0; base < n; base += 1024) {
    int i = base + (int)threadIdx.x;
    int v = (i < n) ? counts[i] : 0;
    lds[threadIdx.x] = v;
    __syncthreads();
    for (int off = 1; off < 1024; off <<= 1) {
      int t = (threadIdx.x >= (unsigned)off) ? lds[threadIdx.x - off] : 0;
      __syncthreads();
      lds[threadIdx.x] += t;
      __syncthreads();
    }
    int incl = lds[threadIdx.x];
    int c0 = carry;
    if (i < n) { int o = c0 + incl - v; offsets[i] = o; cursors[i] = o; }
    __syncthreads();
    if (threadIdx.x == 0) carry += lds[1023];
    __syncthreads();
  }
  if (threadIdx.x == 0) offsets[n] = carry;
}

__global__ __launch_bounds__(256) void fill_kernel(const int* __restrict__ ei,
                                                   int* __restrict__ cursors,
                                                   int* __restrict__ list, int E) {
  int e = blockIdx.x * 256 + threadIdx.x;
  if (e < E) {
    int d = ei[E + e];
    int pos = atomicAdd(&cursors[d], 1);
    list[pos] = ei[e];
  }
}

// ---- fp32 tiled GEMM: C[M,N] = A[M,K] @ B[K,N]  (K%16==0, N%64==0) --------

__global__ __launch_bounds__(256) void gemm_tiled(const float* __restrict__ A,
                                                  const float* __restrict__ B,
                                                  float* __restrict__ C,
                                                  int M, int N, int K) {
  __shared__ float As[16][64];  // [k][m]
  __shared__ float Bs[16][64];  // [k][n]
  int t = threadIdx.x;
  int m0 = blockIdx.x * 64;
  int n0 = blockIdx.y * 64;
  int ty = t >> 4, tx = t & 15;
  float acc[4][4] = {};
  for (int k0 = 0; k0 < K; k0 += 16) {
    {
      int m = t >> 2;
      int kk = (t & 3) * 4;
      int gm = m0 + m;
      float4 v = make_float4(0.f, 0.f, 0.f, 0.f);
      if (gm < M) v = *(const float4*)&A[(size_t)gm * K + k0 + kk];
      As[kk + 0][m] = v.x; As[kk + 1][m] = v.y;
      As[kk + 2][m] = v.z; As[kk + 3][m] = v.w;
    }
    {
      int kk = t >> 4;
      int nn = (t & 15) * 4;
      *(float4*)&Bs[kk][nn] = *(const float4*)&B[(size_t)(k0 + kk) * N + n0 + nn];
    }
    __syncthreads();
#pragma unroll
    for (int kk = 0; kk < 16; ++kk) {
      float4 a = *(const float4*)&As[kk][ty * 4];
      float4 b = *(const float4*)&Bs[kk][tx * 4];
      acc[0][0] += a.x * b.x; acc[0][1] += a.x * b.y; acc[0][2] += a.x * b.z; acc[0][3] += a.x * b.w;
      acc[1][0] += a.y * b.x; acc[1][1] += a.y * b.y; acc[1][2] += a.y * b.z; acc[1][3] += a.y * b.w;
      acc[2][0] += a.z * b.x; acc[2][1] += a.z * b.y; acc[2][2] += a.z * b.z; acc[2][3] += a.z * b.w;
      acc[3][0] += a.w * b.x; acc[3][1] += a.w * b.y; acc[3][2] += a.w * b.z; acc[3][3] += a.w * b.w;
    }
    __syncthreads();
  }
#pragma unroll
  for (int i = 0; i < 4; ++i) {
    int gm = m0 + ty * 4 + i;
    if (gm < M) {
      float4 v = make_float4(acc[i][0], acc[i][1], acc[i][2], acc[i][3]);
      *(float4*)&C[(size_t)gm * N + n0 + tx * 4] = v;
    }
  }
}

// ---- attention dot products ----------------------------------------------

__global__ __launch_bounds__(256) void att1_kernel(const float* __restrict__ h1,
                                                   const float* __restrict__ asrc,
                                                   const float* __restrict__ adst,
                                                   float* __restrict__ a_s,
                                                   float* __restrict__ a_d, int n) {
  int node = blockIdx.x;
  int g = threadIdx.x >> 5, l = threadIdx.x & 31;  // head g, lane-in-group l
  const float* hr = h1 + (size_t)node * 1024 + g * 128;
  float s = 0.f, d = 0.f;
  for (int c = l; c < 128; c += 32) {
    float hv = hr[c];
    s += hv * asrc[g * 128 + c];
    d += hv * adst[g * 128 + c];
  }
  for (int o = 16; o; o >>= 1) { s += __shfl_xor(s, o, 32); d += __shfl_xor(d, o, 32); }
  if (l == 0) { a_s[node * 8 + g] = s; a_d[node * 8 + g] = d; }
}

__global__ __launch_bounds__(256) void att2_kernel(const float* __restrict__ h2,
                                                   const float* __restrict__ asrc,
                                                   const float* __restrict__ adst,
                                                   float* __restrict__ a_s,
                                                   float* __restrict__ a_d, int n) {
  int w = threadIdx.x >> 6, lane = threadIdx.x & 63;
  int node = blockIdx.x * 4 + w;
  if (node >= n) return;
  float hv = h2[(size_t)node * 64 + lane];
  float s = hv * asrc[lane], d = hv * adst[lane];
  for (int o = 32; o; o >>= 1) { s += __shfl_xor(s, o); d += __shfl_xor(d, o); }
  if (lane == 0) { a_s[node] = s; a_d[node] = d; }
}

// ---- layer-1 aggregation (8 heads x 128 ch), fused bias+ELU ---------------

#define CH 64
__global__ __launch_bounds__(256) void agg1_kernel(const float* __restrict__ h1,
                                                   const float* __restrict__ a_s,
                                                   const float* __restrict__ a_d,
                                                   const int* __restrict__ offsets,
                                                   const int* __restrict__ list,
                                                   const float* __restrict__ b1,
                                                   float* __restrict__ out1, int n) {
  int node = blockIdx.x;
  int t = threadIdx.x;
  int beg = offsets[node];
  int deg = offsets[node + 1] - beg;
  int tot = deg + 1;  // + self loop
  __shared__ float m_h[8], den_h[8];
  __shared__ int src_s[CH];
  __shared__ float alpha_s[CH][8];

  int g = t >> 5, l = t & 31;  // head g
  float ad = a_d[node * 8 + g];
  float mx = -3.4e38f;
  for (int i = l; i < tot; i += 32) {
    int s = (i < deg) ? list[beg + i] : node;
    mx = fmaxf(mx, lrelu(a_s[s * 8 + g] + ad));
  }
  for (int o = 16; o; o >>= 1) mx = fmaxf(mx, __shfl_xor(mx, o, 32));
  float sum = 0.f;
  for (int i = l; i < tot; i += 32) {
    int s = (i < deg) ? list[beg + i] : node;
    sum += expf(lrelu(a_s[s * 8 + g] + ad) - mx);
  }
  for (int o = 16; o; o >>= 1) sum += __shfl_xor(sum, o, 32);
  if (l == 0) { m_h[g] = mx; den_h[g] = sum + 1e-16f; }
  __syncthreads();

  float acc0 = 0.f, acc1 = 0.f, acc2 = 0.f, acc3 = 0.f;
  for (int c0 = 0; c0 < tot; c0 += CH) {
    int cnt = min(CH, tot - c0);
    if (t < cnt) { int i = c0 + t; src_s[t] = (i < deg) ? list[beg + i] : node; }
    __syncthreads();
    for (int idx = t; idx < cnt * 8; idx += 256) {
      int j = idx >> 3, h = idx & 7;
      int s = src_s[j];
      float e = lrelu(a_s[s * 8 + h] + a_d[node * 8 + h]);
      alpha_s[j][h] = expf(e - m_h[h]) / den_h[h];
    }
    __syncthreads();
    for (int j = 0; j < cnt; ++j) {
      const float* hr = h1 + (size_t)src_s[j] * 1024;
      acc0 += alpha_s[j][(t) >> 7] * hr[t];
      acc1 += alpha_s[j][(t + 256) >> 7] * hr[t + 256];
      acc2 += alpha_s[j][(t + 512) >> 7] * hr[t + 512];
      acc3 += alpha_s[j][(t + 768) >> 7] * hr[t + 768];
    }
    __syncthreads();
  }
  size_t ob = (size_t)node * 1024;
  float v;
  v = acc0 + b1[t];       out1[ob + t]       = v > 0.f ? v : expm1f(v);
  v = acc1 + b1[t + 256]; out1[ob + t + 256] = v > 0.f ? v : expm1f(v);
  v = acc2 + b1[t + 512]; out1[ob + t + 512] = v > 0.f ? v : expm1f(v);
  v = acc3 + b1[t + 768]; out1[ob + t + 768] = v > 0.f ? v : expm1f(v);
}

// ---- layer-2 aggregation (1 head x 64 ch), fused bias, writes d_out -------

__global__ __launch_bounds__(256) void agg2_kernel(const float* __restrict__ h2,
                                                   const float* __restrict__ a_s,
                                                   const float* __restrict__ a_d,
                                                   const int* __restrict__ offsets,
                                                   const int* __restrict__ list,
                                                   const float* __restrict__ b2,
                                                   float* __restrict__ out, int n) {
  int w = threadIdx.x >> 6, lane = threadIdx.x & 63;
  int node = blockIdx.x * 4 + w;
  if (node >= n) return;
  int beg = offsets[node];
  int deg = offsets[node + 1] - beg;
  int tot = deg + 1;
  float ad = a_d[node];
  float mx = -3.4e38f;
  for (int i = lane; i < tot; i += 64) {
    int s = (i < deg) ? list[beg + i] : node;
    mx = fmaxf(mx, lrelu(a_s[s] + ad));
  }
  for (int o = 32; o; o >>= 1) mx = fmaxf(mx, __shfl_xor(mx, o));
  float sum = 0.f;
  for (int i = lane; i < tot; i += 64) {
    int s = (i < deg) ? list[beg + i] : node;
    sum += expf(lrelu(a_s[s] + ad) - mx);
  }
  for (int o = 32; o; o >>= 1) sum += __shfl_xor(sum, o);
  float den = sum + 1e-16f;
  float acc = 0.f;
  for (int i = 0; i < tot; ++i) {
    int s = (i < deg) ? list[beg + i] : node;
    float al = expf(lrelu(a_s[s] + ad) - mx) / den;
    acc += al * h2[(size_t)s * 64 + lane];
  }
  out[(size_t)node * 64 + lane] = acc + b2[lane];
}

// ---------------------------------------------------------------------------

extern "C" void kernel_launch(void* const* d_in, const int* in_sizes, int n_in,
                              void* d_out, int out_size, void* d_ws, size_t ws_size,
                              hipStream_t stream) {
  const float* x     = (const float*)d_in[0];
  const int*   ei    = (const int*)d_in[1];
  const float* W1    = (const float*)d_in[2];
  const float* asrc1 = (const float*)d_in[3];
  const float* adst1 = (const float*)d_in[4];
  const float* b1    = (const float*)d_in[5];
  const float* W2    = (const float*)d_in[6];
  const float* asrc2 = (const float*)d_in[7];
  const float* adst2 = (const float*)d_in[8];
  const float* b2    = (const float*)d_in[9];
  float* out = (float*)d_out;

  const int N = in_sizes[0] / 256;
  const int E = in_sizes[1] / 2;

  char* p = (char*)d_ws;
  auto bump = [&](size_t bytes) {
    char* r = p;
    p += (bytes + 255) & ~(size_t)255;
    return r;
  };
  int* counts  = (int*)bump((size_t)N * 4);
  int* offsets = (int*)bump((size_t)(N + 1) * 4);
  int* cursors = (int*)bump((size_t)N * 4);
  int* list    = (int*)bump((size_t)E * 4);
  float* h1    = (float*)bump((size_t)N * 1024 * 4);
  float* as1   = (float*)bump((size_t)N * 8 * 4);
  float* ad1   = (float*)bump((size_t)N * 8 * 4);
  float* out1  = (float*)bump((size_t)N * 1024 * 4);
  float* h2    = (float*)bump((size_t)N * 64 * 4);
  float* as2   = (float*)bump((size_t)N * 4);
  float* ad2   = (float*)bump((size_t)N * 4);

  hipMemsetAsync(counts, 0, (size_t)N * 4, stream);
  count_kernel<<<(E + 255) / 256, 256, 0, stream>>>(ei, counts, E);
  scan_kernel<<<1, 1024, 0, stream>>>(counts, offsets, cursors, N);
  fill_kernel<<<(E + 255) / 256, 256, 0, stream>>>(ei, cursors, list, E);

  // layer 1
  gemm_tiled<<<dim3((N + 63) / 64, 1024 / 64), 256, 0, stream>>>(x, W1, h1, N, 1024, 256);
  att1_kernel<<<N, 256, 0, stream>>>(h1, asrc1, adst1, as1, ad1, N);
  agg1_kernel<<<N, 256, 0, stream>>>(h1, as1, ad1, offsets, list, b1, out1, N);

  // layer 2
  gemm_tiled<<<dim3((N + 63) / 64, 1), 256, 0, stream>>>(out1, W2, h2, N, 64, 1024);
  att2_kernel<<<(N + 3) / 4, 256, 0, stream>>>(h2, asrc2, adst2, as2, ad2, N);
  agg2_kernel<<<(N + 3) / 4, 256, 0, stream>>>(h2, as2, ad2, offsets, list, b2, out, N);
}

// Round 2
// 336.861 us; speedup vs baseline: 1.0158x; 1.0158x over previous
//
#include <hip/hip_runtime.h>
#include <cmath>

// ---------------------------------------------------------------------------
// 2-layer GAT, N=10000, E=160000(+self loops), F_IN=256 -> [8x128 concat]=1024
// -> ELU -> [1x64]. Split-bf16 MFMA GEMMs (3-term, fp32-accurate), fused
// attention-dot epilogues, bf16 message gather.
// ---------------------------------------------------------------------------

typedef short bf16x8 __attribute__((ext_vector_type(8)));
typedef float f32x4 __attribute__((ext_vector_type(4)));

__device__ __forceinline__ float lrelu(float x) { return x > 0.f ? x : 0.2f * x; }
__device__ __forceinline__ float b2f(unsigned short h) {
  return __uint_as_float(((unsigned)h) << 16);
}
__device__ __forceinline__ unsigned short f2bf(float f) {
  unsigned u = __float_as_uint(f);
  u += 0x7FFFu + ((u >> 16) & 1u);
  return (unsigned short)(u >> 16);
}

// ---- CSR build ------------------------------------------------------------

__global__ __launch_bounds__(256) void count_kernel(const int* __restrict__ ei,
                                                    int* __restrict__ counts, int E) {
  int e = blockIdx.x * 256 + threadIdx.x;
  if (e < E) atomicAdd(&counts[ei[E + e]], 1);
}

__global__ __launch_bounds__(1024) void scan_kernel(const int* __restrict__ counts,
                                                    int* __restrict__ offsets,
                                                    int* __restrict__ cursors, int n) {
  __shared__ int lds[1024];
  __shared__ int carry;
  if (threadIdx.x == 0) carry = 0;
  __syncthreads();
  for (int base = 0; base < n; base += 1024) {
    int i = base + (int)threadIdx.x;
    int v = (i < n) ? counts[i] : 0;
    lds[threadIdx.x] = v;
    __syncthreads();
    for (int off = 1; off < 1024; off <<= 1) {
      int t = (threadIdx.x >= (unsigned)off) ? lds[threadIdx.x - off] : 0;
      __syncthreads();
      lds[threadIdx.x] += t;
      __syncthreads();
    }
    int incl = lds[threadIdx.x];
    int c0 = carry;
    if (i < n) { int o = c0 + incl - v; offsets[i] = o; cursors[i] = o; }
    __syncthreads();
    if (threadIdx.x == 0) carry += lds[1023];
    __syncthreads();
  }
  if (threadIdx.x == 0) offsets[n] = carry;
}

__global__ __launch_bounds__(256) void fill_kernel(const int* __restrict__ ei,
                                                   int* __restrict__ cursors,
                                                   int* __restrict__ list, int E) {
  int e = blockIdx.x * 256 + threadIdx.x;
  if (e < E) {
    int d = ei[E + e];
    int pos = atomicAdd(&cursors[d], 1);
    list[pos] = ei[e];
  }
}

// ---- prep: split x (zero-padded rows), transpose+split weights ------------

__global__ __launch_bounds__(256) void split_x(const float* __restrict__ x,
                                               unsigned short* __restrict__ xh,
                                               unsigned short* __restrict__ xl, int N) {
  int row = blockIdx.x, t = threadIdx.x;
  float v = (row < N) ? x[(size_t)row * 256 + t] : 0.f;
  unsigned short hi = f2bf(v);
  unsigned short lo = f2bf(v - b2f(hi));
  size_t idx = (size_t)row * 256 + t;
  xh[idx] = hi; xl[idx] = lo;
}

__global__ __launch_bounds__(256) void tsplit_w1(const float* __restrict__ W,
                                                 unsigned short* __restrict__ ht,
                                                 unsigned short* __restrict__ lt) {
  int n = blockIdx.x, k = threadIdx.x;          // W [256][1024] -> Wt [1024][256]
  float v = W[(size_t)k * 1024 + n];
  unsigned short hi = f2bf(v);
  unsigned short lo = f2bf(v - b2f(hi));
  ht[(size_t)n * 256 + k] = hi; lt[(size_t)n * 256 + k] = lo;
}

__global__ __launch_bounds__(256) void tsplit_w2(const float* __restrict__ W,
                                                 unsigned short* __restrict__ ht,
                                                 unsigned short* __restrict__ lt) {
  int c = blockIdx.x, t = threadIdx.x;          // W [1024][64] -> Wt [64][1024]
  for (int r = 0; r < 4; ++r) {
    int k = r * 256 + t;
    float v = W[(size_t)k * 64 + c];
    unsigned short hi = f2bf(v);
    unsigned short lo = f2bf(v - b2f(hi));
    ht[(size_t)c * 1024 + k] = hi; lt[(size_t)c * 1024 + k] = lo;
  }
}

// ---- GEMM1 (split-bf16 MFMA) + fused att1 dots ----------------------------
// C[m, hb*128+col] for m in [m0,m0+64), one head-block per blockIdx.y.
// BM=64, BN=128, BK=32. 4 waves across N (WN=32). LDS buf 24 KB x2.

__global__ __launch_bounds__(256) void gemm1_att(
    const unsigned short* __restrict__ xh, const unsigned short* __restrict__ xl,
    const unsigned short* __restrict__ w1ht, const unsigned short* __restrict__ w1lt,
    const float* __restrict__ asrc, const float* __restrict__ adst,
    unsigned short* __restrict__ h1b, float* __restrict__ as1,
    float* __restrict__ ad1) {
  extern __shared__ char sm[];
  const int t = threadIdx.x, wid = t >> 6, lane = t & 63;
  const int m0 = blockIdx.x * 64, hb = blockIdx.y;
  const int l15 = lane & 15, l4 = lane >> 4;

  f32x4 acc[4][2] = {};

  auto stage = [&](int buf, int k0) {
    char* base0 = sm + buf * 24576;
    for (int i = wid; i < 24; i += 4) {
      const unsigned short* src;
      size_t goff;
      int ldsoff;
      if (i < 8) {                                  // A subtiles (hi/lo)
        int arr = i >> 2, f = i & 3;
        src = arr ? xl : xh;
        goff = (size_t)(m0 + f * 16 + l15) * 256 + k0 + l4 * 8;
        ldsoff = arr * 4096 + f * 1024;
      } else {                                      // B subtiles (hi/lo)
        int j = i - 8, arr = j >> 3, g = j & 7;
        src = arr ? w1lt : w1ht;
        goff = (size_t)(hb * 128 + g * 16 + l15) * 256 + k0 + l4 * 8;
        ldsoff = 8192 + arr * 8192 + g * 1024;
      }
      __builtin_amdgcn_global_load_lds(
          (const __attribute__((address_space(1))) unsigned int*)(src + goff),
          (__attribute__((address_space(3))) unsigned int*)(base0 + ldsoff),
          16, 0, 0);
    }
  };

  stage(0, 0);
  __syncthreads();
  int buf = 0;
  for (int step = 0; step < 8; ++step) {
    if (step < 7) stage(buf ^ 1, (step + 1) * 32);
    const char* b = sm + buf * 24576;
    bf16x8 ah[4], al[4], bh[2], bl[2];
#pragma unroll
    for (int mf = 0; mf < 4; ++mf) {
      ah[mf] = *(const bf16x8*)(b + mf * 1024 + lane * 16);
      al[mf] = *(const bf16x8*)(b + 4096 + mf * 1024 + lane * 16);
    }
#pragma unroll
    for (int nf = 0; nf < 2; ++nf) {
      int g = wid * 2 + nf;
      bh[nf] = *(const bf16x8*)(b + 8192 + g * 1024 + lane * 16);
      bl[nf] = *(const bf16x8*)(b + 16384 + g * 1024 + lane * 16);
    }
#pragma unroll
    for (int mf = 0; mf < 4; ++mf)
#pragma unroll
      for (int nf = 0; nf < 2; ++nf) {
        acc[mf][nf] = __builtin_amdgcn_mfma_f32_16x16x32_bf16(ah[mf], bh[nf], acc[mf][nf], 0, 0, 0);
        acc[mf][nf] = __builtin_amdgcn_mfma_f32_16x16x32_bf16(ah[mf], bl[nf], acc[mf][nf], 0, 0, 0);
        acc[mf][nf] = __builtin_amdgcn_mfma_f32_16x16x32_bf16(al[mf], bh[nf], acc[mf][nf], 0, 0, 0);
      }
    __syncthreads();
    buf ^= 1;
  }

  // epilogue: fused att dots (fp32 acc) + bf16 C-tile via LDS (coalesced out)
  float* parts_s = (float*)sm;                       // [64][4]
  float* parts_d = (float*)(sm + 1024);              // [64][4]
  unsigned short* ctile = (unsigned short*)(sm + 2048);  // [64][128]
  float as_c[2], ad_c[2];
#pragma unroll
  for (int nf = 0; nf < 2; ++nf) {
    int col = hb * 128 + wid * 32 + nf * 16 + l15;
    as_c[nf] = asrc[col];
    ad_c[nf] = adst[col];
  }
#pragma unroll
  for (int mf = 0; mf < 4; ++mf) {
    float ss[4] = {0.f, 0.f, 0.f, 0.f}, dd[4] = {0.f, 0.f, 0.f, 0.f};
#pragma unroll
    for (int nf = 0; nf < 2; ++nf)
#pragma unroll
      for (int r = 0; r < 4; ++r) {
        ss[r] += acc[mf][nf][r] * as_c[nf];
        dd[r] += acc[mf][nf][r] * ad_c[nf];
      }
#pragma unroll
    for (int r = 0; r < 4; ++r)
      for (int m = 1; m < 16; m <<= 1) {
        ss[r] += __shfl_xor(ss[r], m);
        dd[r] += __shfl_xor(dd[r], m);
      }
    if (l15 == 0) {
#pragma unroll
      for (int r = 0; r < 4; ++r) {
        int row = mf * 16 + l4 * 4 + r;
        parts_s[row * 4 + wid] = ss[r];
        parts_d[row * 4 + wid] = dd[r];
      }
    }
#pragma unroll
    for (int nf = 0; nf < 2; ++nf)
#pragma unroll
      for (int r = 0; r < 4; ++r) {
        int row = mf * 16 + l4 * 4 + r;
        int col = wid * 32 + nf * 16 + l15;
        ctile[row * 128 + col] = f2bf(acc[mf][nf][r]);
      }
  }
  __syncthreads();
  if (t < 64) {
    float s = parts_s[t * 4] + parts_s[t * 4 + 1] + parts_s[t * 4 + 2] + parts_s[t * 4 + 3];
    float d = parts_d[t * 4] + parts_d[t * 4 + 1] + parts_d[t * 4 + 2] + parts_d[t * 4 + 3];
    as1[(size_t)(m0 + t) * 8 + hb] = s;
    ad1[(size_t)(m0 + t) * 8 + hb] = d;
  }
#pragma unroll
  for (int rep = 0; rep < 4; ++rep) {
    int e = rep * 2048 + t * 8;
    int row = e >> 7, col = e & 127;
    bf16x8 v = *(const bf16x8*)(ctile + e);
    *(bf16x8*)(h1b + (size_t)(m0 + row) * 1024 + hb * 128 + col) = v;
  }
}

// ---- GEMM2 (split-bf16 MFMA) + fused att2 dots ----------------------------
// BM=64, BN=64 (full width), BK=32, 4 waves 2x2 (WM=32, WN=32).

__global__ __launch_bounds__(256) void gemm2_att(
    const unsigned short* __restrict__ o1h, const unsigned short* __restrict__ o1l,
    const unsigned short* __restrict__ w2ht, const unsigned short* __restrict__ w2lt,
    const float* __restrict__ asrc, const float* __restrict__ adst,
    float* __restrict__ h2, float* __restrict__ as2, float* __restrict__ ad2) {
  extern __shared__ char sm[];
  const int t = threadIdx.x, wid = t >> 6, lane = t & 63;
  const int wr = wid >> 1, wc = wid & 1;
  const int m0 = blockIdx.x * 64;
  const int l15 = lane & 15, l4 = lane >> 4;

  f32x4 acc[2][2] = {};

  auto stage = [&](int buf, int k0) {
    char* base0 = sm + buf * 16384;
    for (int i = wid; i < 16; i += 4) {
      const unsigned short* src;
      size_t goff;
      int ldsoff;
      if (i < 8) {
        int arr = i >> 2, f = i & 3;
        src = arr ? o1l : o1h;
        goff = (size_t)(m0 + f * 16 + l15) * 1024 + k0 + l4 * 8;
        ldsoff = arr * 4096 + f * 1024;
      } else {
        int j = i - 8, arr = j >> 2, g = j & 3;
        src = arr ? w2lt : w2ht;
        goff = (size_t)(g * 16 + l15) * 1024 + k0 + l4 * 8;
        ldsoff = 8192 + arr * 4096 + g * 1024;
      }
      __builtin_amdgcn_global_load_lds(
          (const __attribute__((address_space(1))) unsigned int*)(src + goff),
          (__attribute__((address_space(3))) unsigned int*)(base0 + ldsoff),
          16, 0, 0);
    }
  };

  stage(0, 0);
  __syncthreads();
  int buf = 0;
  for (int step = 0; step < 32; ++step) {
    if (step < 31) stage(buf ^ 1, (step + 1) * 32);
    const char* b = sm + buf * 16384;
    bf16x8 ah[2], al[2], bh[2], bl[2];
#pragma unroll
    for (int mf = 0; mf < 2; ++mf) {
      int f = wr * 2 + mf;
      ah[mf] = *(const bf16x8*)(b + f * 1024 + lane * 16);
      al[mf] = *(const bf16x8*)(b + 4096 + f * 1024 + lane * 16);
    }
#pragma unroll
    for (int nf = 0; nf < 2; ++nf) {
      int g = wc * 2 + nf;
      bh[nf] = *(const bf16x8*)(b + 8192 + g * 1024 + lane * 16);
      bl[nf] = *(const bf16x8*)(b + 12288 + g * 1024 + lane * 16);
    }
#pragma unroll
    for (int mf = 0; mf < 2; ++mf)
#pragma unroll
      for (int nf = 0; nf < 2; ++nf) {
        acc[mf][nf] = __builtin_amdgcn_mfma_f32_16x16x32_bf16(ah[mf], bh[nf], acc[mf][nf], 0, 0, 0);
        acc[mf][nf] = __builtin_amdgcn_mfma_f32_16x16x32_bf16(ah[mf], bl[nf], acc[mf][nf], 0, 0, 0);
        acc[mf][nf] = __builtin_amdgcn_mfma_f32_16x16x32_bf16(al[mf], bh[nf], acc[mf][nf], 0, 0, 0);
      }
    __syncthreads();
    buf ^= 1;
  }

  float* parts_s = (float*)sm;          // [64][2]
  float* parts_d = (float*)(sm + 512);  // [64][2]
  float as_c[2], ad_c[2];
#pragma unroll
  for (int nf = 0; nf < 2; ++nf) {
    int col = wc * 32 + nf * 16 + l15;
    as_c[nf] = asrc[col];
    ad_c[nf] = adst[col];
  }
#pragma unroll
  for (int mf = 0; mf < 2; ++mf) {
    float ss[4] = {0.f, 0.f, 0.f, 0.f}, dd[4] = {0.f, 0.f, 0.f, 0.f};
#pragma unroll
    for (int nf = 0; nf < 2; ++nf)
#pragma unroll
      for (int r = 0; r < 4; ++r) {
        ss[r] += acc[mf][nf][r] * as_c[nf];
        dd[r] += acc[mf][nf][r] * ad_c[nf];
      }
#pragma unroll
    for (int r = 0; r < 4; ++r)
      for (int m = 1; m < 16; m <<= 1) {
        ss[r] += __shfl_xor(ss[r], m);
        dd[r] += __shfl_xor(dd[r], m);
      }
    if (l15 == 0) {
#pragma unroll
      for (int r = 0; r < 4; ++r) {
        int row = wr * 32 + mf * 16 + l4 * 4 + r;
        parts_s[row * 2 + wc] = ss[r];
        parts_d[row * 2 + wc] = dd[r];
      }
    }
#pragma unroll
    for (int nf = 0; nf < 2; ++nf)
#pragma unroll
      for (int r = 0; r < 4; ++r) {
        int row = wr * 32 + mf * 16 + l4 * 4 + r;
        int col = wc * 32 + nf * 16 + l15;
        h2[(size_t)(m0 + row) * 64 + col] = acc[mf][nf][r];
      }
  }
  __syncthreads();
  if (t < 64) {
    as2[m0 + t] = parts_s[t * 2] + parts_s[t * 2 + 1];
    ad2[m0 + t] = parts_d[t * 2] + parts_d[t * 2 + 1];
  }
}

// ---- layer-1 aggregation: bf16 gather, fused bias+ELU, split-bf16 out -----

__global__ __launch_bounds__(256) void agg1_kernel(
    const unsigned short* __restrict__ h1b, const float* __restrict__ a_s,
    const float* __restrict__ a_d, const int* __restrict__ offsets,
    const int* __restrict__ list, const float* __restrict__ b1,
    unsigned short* __restrict__ o1h, unsigned short* __restrict__ o1l, int n) {
  int node = blockIdx.x;
  int t = threadIdx.x;
  int beg = offsets[node];
  int deg = offsets[node + 1] - beg;
  int tot = deg + 1;  // + self loop
  __shared__ float m_h[8], den_h[8];
  __shared__ int src_s[64];
  __shared__ float alpha_s[64][8];

  int g = t >> 5, l = t & 31;
  float ad = a_d[(size_t)node * 8 + g];
  float mx = -3.4e38f;
  for (int i = l; i < tot; i += 32) {
    int s = (i < deg) ? list[beg + i] : node;
    mx = fmaxf(mx, lrelu(a_s[(size_t)s * 8 + g] + ad));
  }
  for (int o = 16; o; o >>= 1) mx = fmaxf(mx, __shfl_xor(mx, o, 32));
  float sum = 0.f;
  for (int i = l; i < tot; i += 32) {
    int s = (i < deg) ? list[beg + i] : node;
    sum += expf(lrelu(a_s[(size_t)s * 8 + g] + ad) - mx);
  }
  for (int o = 16; o; o >>= 1) sum += __shfl_xor(sum, o, 32);
  if (l == 0) { m_h[g] = mx; den_h[g] = sum + 1e-16f; }
  __syncthreads();

  float acc0 = 0.f, acc1 = 0.f, acc2 = 0.f, acc3 = 0.f;
  int hsel = t >> 5;  // head of channels 4t..4t+3
  for (int c0 = 0; c0 < tot; c0 += 64) {
    int cnt = min(64, tot - c0);
    if (t < cnt) { int i = c0 + t; src_s[t] = (i < deg) ? list[beg + i] : node; }
    __syncthreads();
    for (int idx = t; idx < cnt * 8; idx += 256) {
      int j = idx >> 3, h = idx & 7;
      int s = src_s[j];
      float e = lrelu(a_s[(size_t)s * 8 + h] + a_d[(size_t)node * 8 + h]);
      alpha_s[j][h] = expf(e - m_h[h]) / den_h[h];
    }
    __syncthreads();
    for (int j = 0; j < cnt; ++j) {
      const ushort4* hp = (const ushort4*)(h1b + (size_t)src_s[j] * 1024) + t;
      ushort4 v = *hp;
      float al = alpha_s[j][hsel];
      acc0 += al * b2f(v.x);
      acc1 += al * b2f(v.y);
      acc2 += al * b2f(v.z);
      acc3 += al * b2f(v.w);
    }
    __syncthreads();
  }
  int c = 4 * t;
  float v0 = acc0 + b1[c], v1 = acc1 + b1[c + 1], v2 = acc2 + b1[c + 2], v3 = acc3 + b1[c + 3];
  v0 = v0 > 0.f ? v0 : expm1f(v0);
  v1 = v1 > 0.f ? v1 : expm1f(v1);
  v2 = v2 > 0.f ? v2 : expm1f(v2);
  v3 = v3 > 0.f ? v3 : expm1f(v3);
  ushort4 hi, lo;
  hi.x = f2bf(v0); lo.x = f2bf(v0 - b2f(hi.x));
  hi.y = f2bf(v1); lo.y = f2bf(v1 - b2f(hi.y));
  hi.z = f2bf(v2); lo.z = f2bf(v2 - b2f(hi.z));
  hi.w = f2bf(v3); lo.w = f2bf(v3 - b2f(hi.w));
  *((ushort4*)(o1h + (size_t)node * 1024) + t) = hi;
  *((ushort4*)(o1l + (size_t)node * 1024) + t) = lo;
}

// ---- layer-2 aggregation (fp32 h2 gather), writes d_out -------------------

__global__ __launch_bounds__(256) void agg2_kernel(
    const float* __restrict__ h2, const float* __restrict__ a_s,
    const float* __restrict__ a_d, const int* __restrict__ offsets,
    const int* __restrict__ list, const float* __restrict__ b2,
    float* __restrict__ out, int n) {
  int w = threadIdx.x >> 6, lane = threadIdx.x & 63;
  int node = blockIdx.x * 4 + w;
  if (node >= n) return;
  int beg = offsets[node];
  int deg = offsets[node + 1] - beg;
  int tot = deg + 1;
  float ad = a_d[node];
  float mx = -3.4e38f;
  for (int i = lane; i < tot; i += 64) {
    int s = (i < deg) ? list[beg + i] : node;
    mx = fmaxf(mx, lrelu(a_s[s] + ad));
  }
  for (int o = 32; o; o >>= 1) mx = fmaxf(mx, __shfl_xor(mx, o));
  float sum = 0.f;
  for (int i = lane; i < tot; i += 64) {
    int s = (i < deg) ? list[beg + i] : node;
    sum += expf(lrelu(a_s[s] + ad) - mx);
  }
  for (int o = 32; o; o >>= 1) sum += __shfl_xor(sum, o);
  float den = sum + 1e-16f;
  float acc = 0.f;
  for (int i = 0; i < tot; ++i) {
    int s = (i < deg) ? list[beg + i] : node;
    float al = expf(lrelu(a_s[s] + ad) - mx) / den;
    acc += al * h2[(size_t)s * 64 + lane];
  }
  out[(size_t)node * 64 + lane] = acc + b2[lane];
}

// ---------------------------------------------------------------------------

extern "C" void kernel_launch(void* const* d_in, const int* in_sizes, int n_in,
                              void* d_out, int out_size, void* d_ws, size_t ws_size,
                              hipStream_t stream) {
  const float* x     = (const float*)d_in[0];
  const int*   ei    = (const int*)d_in[1];
  const float* W1    = (const float*)d_in[2];
  const float* asrc1 = (const float*)d_in[3];
  const float* adst1 = (const float*)d_in[4];
  const float* b1    = (const float*)d_in[5];
  const float* W2    = (const float*)d_in[6];
  const float* asrc2 = (const float*)d_in[7];
  const float* adst2 = (const float*)d_in[8];
  const float* b2    = (const float*)d_in[9];
  float* out = (float*)d_out;

  const int N = in_sizes[0] / 256;
  const int E = in_sizes[1] / 2;
  const int MB1 = (N + 63) / 64;
  const int Mpad = MB1 * 64;

  char* p = (char*)d_ws;
  auto bump = [&](size_t bytes) {
    char* r = p;
    p += (bytes + 255) & ~(size_t)255;
    return r;
  };
  int* counts  = (int*)bump((size_t)N * 4);
  int* offsets = (int*)bump((size_t)(N + 1) * 4);
  int* cursors = (int*)bump((size_t)N * 4);
  int* list    = (int*)bump((size_t)E * 4);
  unsigned short* xh    = (unsigned short*)bump((size_t)Mpad * 256 * 2);
  unsigned short* xl    = (unsigned short*)bump((size_t)Mpad * 256 * 2);
  unsigned short* w1ht  = (unsigned short*)bump((size_t)1024 * 256 * 2);
  unsigned short* w1lt  = (unsigned short*)bump((size_t)1024 * 256 * 2);
  unsigned short* h1b   = (unsigned short*)bump((size_t)Mpad * 1024 * 2);
  float* as1            = (float*)bump((size_t)Mpad * 8 * 4);
  float* ad1            = (float*)bump((size_t)Mpad * 8 * 4);
  unsigned short* o1h   = (unsigned short*)bump((size_t)Mpad * 1024 * 2);
  unsigned short* o1l   = (unsigned short*)bump((size_t)Mpad * 1024 * 2);
  unsigned short* w2ht  = (unsigned short*)bump((size_t)64 * 1024 * 2);
  unsigned short* w2lt  = (unsigned short*)bump((size_t)64 * 1024 * 2);
  float* h2             = (float*)bump((size_t)Mpad * 64 * 4);
  float* as2            = (float*)bump((size_t)Mpad * 4);
  float* ad2            = (float*)bump((size_t)Mpad * 4);

  // CSR
  hipMemsetAsync(counts, 0, (size_t)N * 4, stream);
  count_kernel<<<(E + 255) / 256, 256, 0, stream>>>(ei, counts, E);
  scan_kernel<<<1, 1024, 0, stream>>>(counts, offsets, cursors, N);
  fill_kernel<<<(E + 255) / 256, 256, 0, stream>>>(ei, cursors, list, E);

  // prep
  split_x<<<Mpad, 256, 0, stream>>>(x, xh, xl, N);
  tsplit_w1<<<1024, 256, 0, stream>>>(W1, w1ht, w1lt);
  tsplit_w2<<<64, 256, 0, stream>>>(W2, w2ht, w2lt);

  // layer 1
  gemm1_att<<<dim3(MB1, 8), 256, 49152, stream>>>(xh, xl, w1ht, w1lt, asrc1, adst1,
                                                  h1b, as1, ad1);
  agg1_kernel<<<N, 256, 0, stream>>>(h1b, as1, ad1, offsets, list, b1, o1h, o1l, N);

  // layer 2
  gemm2_att<<<MB1, 256, 32768, stream>>>(o1h, o1l, w2ht, w2lt, asrc2, adst2, h2, as2, ad2);
  agg2_kernel<<<(N + 3) / 4, 256, 0, stream>>>(h2, as2, ad2, offsets, list, b2, out, N);
}

// Round 3
// 208.472 us; speedup vs baseline: 1.6415x; 1.6159x over previous
//
#include <hip/hip_runtime.h>
#include <cmath>

// ---------------------------------------------------------------------------
// 2-layer GAT, N=10000, E=160000(+self loops), F_IN=256 -> [8x128 concat]=1024
// -> ELU -> [1x64]. Split-bf16 MFMA GEMMs (3-term), tile-linear packed
// operands so every global_load_lds is lane-contiguous 1KB, split-K GEMM2.
// ---------------------------------------------------------------------------

typedef short bf16x8 __attribute__((ext_vector_type(8)));
typedef float f32x4 __attribute__((ext_vector_type(4)));
typedef unsigned short u16x8 __attribute__((ext_vector_type(8)));

__device__ __forceinline__ float lrelu(float x) { return x > 0.f ? x : 0.2f * x; }
__device__ __forceinline__ float b2f(unsigned short h) {
  return __uint_as_float(((unsigned)h) << 16);
}
__device__ __forceinline__ unsigned short f2bf(float f) {
  unsigned u = __float_as_uint(f);
  u += 0x7FFFu + ((u >> 16) & 1u);
  return (unsigned short)(u >> 16);
}

#define GLOAD_LDS16(gsrc, ldst)                                              \
  __builtin_amdgcn_global_load_lds(                                          \
      (const __attribute__((address_space(1))) unsigned int*)(gsrc),         \
      (__attribute__((address_space(3))) unsigned int*)(ldst), 16, 0, 0)

// ---- CSR build ------------------------------------------------------------

__global__ __launch_bounds__(256) void count_kernel(const int* __restrict__ ei,
                                                    int* __restrict__ counts, int E) {
  int e = blockIdx.x * 256 + threadIdx.x;
  if (e < E) atomicAdd(&counts[ei[E + e]], 1);
}

__global__ __launch_bounds__(1024) void scan_kernel(const int* __restrict__ counts,
                                                    int* __restrict__ offsets,
                                                    int* __restrict__ cursors, int n) {
  __shared__ int lds[1024];
  __shared__ int carry;
  if (threadIdx.x == 0) carry = 0;
  __syncthreads();
  for (int base = 0; base < n; base += 1024) {
    int i = base + (int)threadIdx.x;
    int v = (i < n) ? counts[i] : 0;
    lds[threadIdx.x] = v;
    __syncthreads();
    for (int off = 1; off < 1024; off <<= 1) {
      int t = (threadIdx.x >= (unsigned)off) ? lds[threadIdx.x - off] : 0;
      __syncthreads();
      lds[threadIdx.x] += t;
      __syncthreads();
    }
    int incl = lds[threadIdx.x];
    int c0 = carry;
    if (i < n) { int o = c0 + incl - v; offsets[i] = o; cursors[i] = o; }
    __syncthreads();
    if (threadIdx.x == 0) carry += lds[1023];
    __syncthreads();
  }
  if (threadIdx.x == 0) offsets[n] = carry;
}

__global__ __launch_bounds__(256) void fill_kernel(const int* __restrict__ ei,
                                                   int* __restrict__ cursors,
                                                   int* __restrict__ list, int E) {
  int e = blockIdx.x * 256 + threadIdx.x;
  if (e < E) {
    int d = ei[E + e];
    int pos = atomicAdd(&cursors[d], 1);
    list[pos] = ei[e];
  }
}

// ---- packing: tile-linear operand layout ----------------------------------
// Subtile = 16(rows) x 32(k) bf16 = 1024B, stored lane-linear: lane l supplies
// (row = l&15, kchunk = l>>4), 16B per lane. Chunk order per (mb,ks):
//   A-type: [4 hi f][4 lo f]; B1: [8 hi g][8 lo g]; B2/A2: [4 hi][4 lo].

__global__ __launch_bounds__(256) void pack_x(const float* __restrict__ x,
                                              unsigned short* __restrict__ xpk, int N) {
  int mb = blockIdx.x, ks = blockIdx.y;
  int t = threadIdx.x, l = t & 63, f = t >> 6;
  int row = mb * 64 + f * 16 + (l & 15);
  int kc = ks * 32 + (l >> 4) * 8;
  float v[8];
#pragma unroll
  for (int j = 0; j < 8; ++j) v[j] = 0.f;
  if (row < N) {
    const float* xr = x + (size_t)row * 256 + kc;
#pragma unroll
    for (int j = 0; j < 8; ++j) v[j] = xr[j];
  }
  u16x8 hi, lo;
#pragma unroll
  for (int j = 0; j < 8; ++j) {
    unsigned short h = f2bf(v[j]);
    hi[j] = h; lo[j] = f2bf(v[j] - b2f(h));
  }
  size_t base = (size_t)(mb * 8 + ks) * 8 * 512;
  *(u16x8*)(xpk + base + (size_t)f * 512 + l * 8) = hi;
  *(u16x8*)(xpk + base + (size_t)(4 + f) * 512 + l * 8) = lo;
}

__global__ __launch_bounds__(256) void pack_w1(const float* __restrict__ W,
                                               unsigned short* __restrict__ wpk) {
  int hb = blockIdx.x, ks = blockIdx.y;
  int t = threadIdx.x, l = t & 63, gq = t >> 6;
  for (int g = gq; g < 8; g += 4) {
    int n = hb * 128 + g * 16 + (l & 15);
    int k0 = ks * 32 + (l >> 4) * 8;
    u16x8 hi, lo;
#pragma unroll
    for (int j = 0; j < 8; ++j) {
      float v = W[(size_t)(k0 + j) * 1024 + n];
      unsigned short h = f2bf(v);
      hi[j] = h; lo[j] = f2bf(v - b2f(h));
    }
    size_t base = (size_t)(hb * 8 + ks) * 16 * 512;
    *(u16x8*)(wpk + base + (size_t)g * 512 + l * 8) = hi;
    *(u16x8*)(wpk + base + (size_t)(8 + g) * 512 + l * 8) = lo;
  }
}

__global__ __launch_bounds__(256) void pack_w2(const float* __restrict__ W,
                                               unsigned short* __restrict__ wpk) {
  int ks = blockIdx.x;
  int t = threadIdx.x, l = t & 63, g = t >> 6;
  int n = g * 16 + (l & 15);
  int k0 = ks * 32 + (l >> 4) * 8;
  u16x8 hi, lo;
#pragma unroll
  for (int j = 0; j < 8; ++j) {
    float v = W[(size_t)(k0 + j) * 64 + n];
    unsigned short h = f2bf(v);
    hi[j] = h; lo[j] = f2bf(v - b2f(h));
  }
  size_t base = (size_t)ks * 8 * 512;
  *(u16x8*)(wpk + base + (size_t)g * 512 + l * 8) = hi;
  *(u16x8*)(wpk + base + (size_t)(4 + g) * 512 + l * 8) = lo;
}

// ---- GEMM1 (split-bf16 MFMA) + fused att1 dots ----------------------------
// BM=64, BN=128 (one head), BK=32, 8 K-steps. LDS/buf: A 8KB | B 16KB.

__global__ __launch_bounds__(256) void gemm1_att(
    const unsigned short* __restrict__ xpk, const unsigned short* __restrict__ w1pk,
    const float* __restrict__ asrc, const float* __restrict__ adst,
    unsigned short* __restrict__ h1b, float* __restrict__ as1,
    float* __restrict__ ad1) {
  extern __shared__ char sm[];
  const int t = threadIdx.x, wid = t >> 6, lane = t & 63;
  const int mb = blockIdx.x, hb = blockIdx.y;
  const int m0 = mb * 64;
  const int l15 = lane & 15, l4 = lane >> 4;

  f32x4 acc[4][2] = {};

  auto stage = [&](int buf, int ks) {
    char* base0 = sm + buf * 24576;
    const unsigned short* ax = xpk + (size_t)(mb * 8 + ks) * 8 * 512 + lane * 8;
    for (int i = wid; i < 8; i += 4)
      GLOAD_LDS16(ax + i * 512, base0 + i * 1024);
    const unsigned short* bw = w1pk + (size_t)(hb * 8 + ks) * 16 * 512 + lane * 8;
    for (int i = wid; i < 16; i += 4)
      GLOAD_LDS16(bw + i * 512, base0 + 8192 + i * 1024);
  };

  stage(0, 0);
  __syncthreads();
  int buf = 0;
  for (int step = 0; step < 8; ++step) {
    if (step < 7) stage(buf ^ 1, step + 1);
    const char* b = sm + buf * 24576;
    bf16x8 ah[4], al[4], bh[2], bl[2];
#pragma unroll
    for (int mf = 0; mf < 4; ++mf) {
      ah[mf] = *(const bf16x8*)(b + mf * 1024 + lane * 16);
      al[mf] = *(const bf16x8*)(b + 4096 + mf * 1024 + lane * 16);
    }
#pragma unroll
    for (int nf = 0; nf < 2; ++nf) {
      int g = wid * 2 + nf;
      bh[nf] = *(const bf16x8*)(b + 8192 + g * 1024 + lane * 16);
      bl[nf] = *(const bf16x8*)(b + 16384 + g * 1024 + lane * 16);
    }
#pragma unroll
    for (int mf = 0; mf < 4; ++mf)
#pragma unroll
      for (int nf = 0; nf < 2; ++nf) {
        acc[mf][nf] = __builtin_amdgcn_mfma_f32_16x16x32_bf16(ah[mf], bh[nf], acc[mf][nf], 0, 0, 0);
        acc[mf][nf] = __builtin_amdgcn_mfma_f32_16x16x32_bf16(ah[mf], bl[nf], acc[mf][nf], 0, 0, 0);
        acc[mf][nf] = __builtin_amdgcn_mfma_f32_16x16x32_bf16(al[mf], bh[nf], acc[mf][nf], 0, 0, 0);
      }
    __syncthreads();
    buf ^= 1;
  }

  // epilogue: fused att dots (fp32 acc) + bf16 C-tile via LDS (coalesced out)
  float* parts_s = (float*)sm;                       // [64][4]
  float* parts_d = (float*)(sm + 1024);              // [64][4]
  unsigned short* ctile = (unsigned short*)(sm + 2048);  // [64][128]
  float as_c[2], ad_c[2];
#pragma unroll
  for (int nf = 0; nf < 2; ++nf) {
    int col = hb * 128 + wid * 32 + nf * 16 + l15;
    as_c[nf] = asrc[col];
    ad_c[nf] = adst[col];
  }
#pragma unroll
  for (int mf = 0; mf < 4; ++mf) {
    float ss[4] = {0.f, 0.f, 0.f, 0.f}, dd[4] = {0.f, 0.f, 0.f, 0.f};
#pragma unroll
    for (int nf = 0; nf < 2; ++nf)
#pragma unroll
      for (int r = 0; r < 4; ++r) {
        ss[r] += acc[mf][nf][r] * as_c[nf];
        dd[r] += acc[mf][nf][r] * ad_c[nf];
      }
#pragma unroll
    for (int r = 0; r < 4; ++r)
      for (int m = 1; m < 16; m <<= 1) {
        ss[r] += __shfl_xor(ss[r], m);
        dd[r] += __shfl_xor(dd[r], m);
      }
    if (l15 == 0) {
#pragma unroll
      for (int r = 0; r < 4; ++r) {
        int row = mf * 16 + l4 * 4 + r;
        parts_s[row * 4 + wid] = ss[r];
        parts_d[row * 4 + wid] = dd[r];
      }
    }
#pragma unroll
    for (int nf = 0; nf < 2; ++nf)
#pragma unroll
      for (int r = 0; r < 4; ++r) {
        int row = mf * 16 + l4 * 4 + r;
        int col = wid * 32 + nf * 16 + l15;
        ctile[row * 128 + col] = f2bf(acc[mf][nf][r]);
      }
  }
  __syncthreads();
  if (t < 64) {
    float s = parts_s[t * 4] + parts_s[t * 4 + 1] + parts_s[t * 4 + 2] + parts_s[t * 4 + 3];
    float d = parts_d[t * 4] + parts_d[t * 4 + 1] + parts_d[t * 4 + 2] + parts_d[t * 4 + 3];
    as1[(size_t)(m0 + t) * 8 + hb] = s;
    ad1[(size_t)(m0 + t) * 8 + hb] = d;
  }
#pragma unroll
  for (int rep = 0; rep < 4; ++rep) {
    int e = rep * 2048 + t * 8;
    int row = e >> 7, col = e & 127;
    bf16x8 v = *(const bf16x8*)(ctile + e);
    *(bf16x8*)(h1b + (size_t)(m0 + row) * 1024 + hb * 128 + col) = v;
  }
}

// ---- GEMM2 (split-bf16 MFMA, split-K=4) -----------------------------------
// BM=64, BN=64, BK=32, 8 K-steps per block. LDS/buf: A 8KB | B 8KB.

__global__ __launch_bounds__(256) void gemm2_splitk(
    const unsigned short* __restrict__ o1pk, const unsigned short* __restrict__ w2pk,
    float* __restrict__ h2p, int Mpad) {
  extern __shared__ char sm[];
  const int t = threadIdx.x, wid = t >> 6, lane = t & 63;
  const int wr = wid >> 1, wc = wid & 1;
  const int mb = blockIdx.x, sk = blockIdx.y;
  const int m0 = mb * 64;
  const int l15 = lane & 15, l4 = lane >> 4;

  f32x4 acc[2][2] = {};

  auto stage = [&](int buf, int ks) {
    char* base0 = sm + buf * 16384;
    const unsigned short* ax = o1pk + (size_t)(mb * 32 + ks) * 8 * 512 + lane * 8;
    for (int i = wid; i < 8; i += 4)
      GLOAD_LDS16(ax + i * 512, base0 + i * 1024);
    const unsigned short* bw = w2pk + (size_t)ks * 8 * 512 + lane * 8;
    for (int i = wid; i < 8; i += 4)
      GLOAD_LDS16(bw + i * 512, base0 + 8192 + i * 1024);
  };

  stage(0, sk * 8);
  __syncthreads();
  int buf = 0;
  for (int step = 0; step < 8; ++step) {
    if (step < 7) stage(buf ^ 1, sk * 8 + step + 1);
    const char* b = sm + buf * 16384;
    bf16x8 ah[2], al[2], bh[2], bl[2];
#pragma unroll
    for (int mf = 0; mf < 2; ++mf) {
      int f = wr * 2 + mf;
      ah[mf] = *(const bf16x8*)(b + f * 1024 + lane * 16);
      al[mf] = *(const bf16x8*)(b + 4096 + f * 1024 + lane * 16);
    }
#pragma unroll
    for (int nf = 0; nf < 2; ++nf) {
      int g = wc * 2 + nf;
      bh[nf] = *(const bf16x8*)(b + 8192 + g * 1024 + lane * 16);
      bl[nf] = *(const bf16x8*)(b + 12288 + g * 1024 + lane * 16);
    }
#pragma unroll
    for (int mf = 0; mf < 2; ++mf)
#pragma unroll
      for (int nf = 0; nf < 2; ++nf) {
        acc[mf][nf] = __builtin_amdgcn_mfma_f32_16x16x32_bf16(ah[mf], bh[nf], acc[mf][nf], 0, 0, 0);
        acc[mf][nf] = __builtin_amdgcn_mfma_f32_16x16x32_bf16(ah[mf], bl[nf], acc[mf][nf], 0, 0, 0);
        acc[mf][nf] = __builtin_amdgcn_mfma_f32_16x16x32_bf16(al[mf], bh[nf], acc[mf][nf], 0, 0, 0);
      }
    __syncthreads();
    buf ^= 1;
  }

#pragma unroll
  for (int mf = 0; mf < 2; ++mf)
#pragma unroll
    for (int nf = 0; nf < 2; ++nf)
#pragma unroll
      for (int r = 0; r < 4; ++r) {
        int row = wr * 32 + mf * 16 + l4 * 4 + r;
        int col = wc * 32 + nf * 16 + l15;
        h2p[((size_t)sk * Mpad + m0 + row) * 64 + col] = acc[mf][nf][r];
      }
}

// ---- reduce split-K partials + att2 dots ----------------------------------

__global__ __launch_bounds__(256) void reduce_att2(
    const float* __restrict__ h2p, const float* __restrict__ asrc,
    const float* __restrict__ adst, float* __restrict__ h2,
    float* __restrict__ as2, float* __restrict__ ad2, int Mpad, int n) {
  int w = threadIdx.x >> 6, lane = threadIdx.x & 63;
  int row = blockIdx.x * 4 + w;
  if (row >= n) return;
  float s = 0.f;
#pragma unroll
  for (int sk = 0; sk < 4; ++sk) s += h2p[((size_t)sk * Mpad + row) * 64 + lane];
  h2[(size_t)row * 64 + lane] = s;
  float ds = s * asrc[lane], dd = s * adst[lane];
  for (int o = 32; o; o >>= 1) { ds += __shfl_xor(ds, o); dd += __shfl_xor(dd, o); }
  if (lane == 0) { as2[row] = ds; ad2[row] = dd; }
}

// ---- layer-1 aggregation: bf16 gather, fused bias+ELU, packed split out ---

__global__ __launch_bounds__(256) void agg1_kernel(
    const unsigned short* __restrict__ h1b, const float* __restrict__ a_s,
    const float* __restrict__ a_d, const int* __restrict__ offsets,
    const int* __restrict__ list, const float* __restrict__ b1,
    unsigned short* __restrict__ o1pk, int n) {
  int node = blockIdx.x;
  int t = threadIdx.x;
  int beg = offsets[node];
  int deg = offsets[node + 1] - beg;
  int tot = deg + 1;  // + self loop
  __shared__ float m_h[8], den_h[8];
  __shared__ int src_s[64];
  __shared__ float alpha_s[64][8];

  int g = t >> 5, l = t & 31;
  float ad = a_d[(size_t)node * 8 + g];
  float mx = -3.4e38f;
  for (int i = l; i < tot; i += 32) {
    int s = (i < deg) ? list[beg + i] : node;
    mx = fmaxf(mx, lrelu(a_s[(size_t)s * 8 + g] + ad));
  }
  for (int o = 16; o; o >>= 1) mx = fmaxf(mx, __shfl_xor(mx, o, 32));
  float sum = 0.f;
  for (int i = l; i < tot; i += 32) {
    int s = (i < deg) ? list[beg + i] : node;
    sum += expf(lrelu(a_s[(size_t)s * 8 + g] + ad) - mx);
  }
  for (int o = 16; o; o >>= 1) sum += __shfl_xor(sum, o, 32);
  if (l == 0) { m_h[g] = mx; den_h[g] = sum + 1e-16f; }
  __syncthreads();

  float acc0 = 0.f, acc1 = 0.f, acc2 = 0.f, acc3 = 0.f;
  int hsel = t >> 5;  // head of channels 4t..4t+3
  for (int c0 = 0; c0 < tot; c0 += 64) {
    int cnt = min(64, tot - c0);
    if (t < cnt) { int i = c0 + t; src_s[t] = (i < deg) ? list[beg + i] : node; }
    __syncthreads();
    for (int idx = t; idx < cnt * 8; idx += 256) {
      int j = idx >> 3, h = idx & 7;
      int s = src_s[j];
      float e = lrelu(a_s[(size_t)s * 8 + h] + a_d[(size_t)node * 8 + h]);
      alpha_s[j][h] = expf(e - m_h[h]) / den_h[h];
    }
    __syncthreads();
    for (int j = 0; j < cnt; ++j) {
      const ushort4* hp = (const ushort4*)(h1b + (size_t)src_s[j] * 1024) + t;
      ushort4 v = *hp;
      float al = alpha_s[j][hsel];
      acc0 += al * b2f(v.x);
      acc1 += al * b2f(v.y);
      acc2 += al * b2f(v.z);
      acc3 += al * b2f(v.w);
    }
    __syncthreads();
  }
  int c = 4 * t;
  float v0 = acc0 + b1[c], v1 = acc1 + b1[c + 1], v2 = acc2 + b1[c + 2], v3 = acc3 + b1[c + 3];
  v0 = v0 > 0.f ? v0 : expm1f(v0);
  v1 = v1 > 0.f ? v1 : expm1f(v1);
  v2 = v2 > 0.f ? v2 : expm1f(v2);
  v3 = v3 > 0.f ? v3 : expm1f(v3);
  ushort4 hi, lo;
  hi.x = f2bf(v0); lo.x = f2bf(v0 - b2f(hi.x));
  hi.y = f2bf(v1); lo.y = f2bf(v1 - b2f(hi.y));
  hi.z = f2bf(v2); lo.z = f2bf(v2 - b2f(hi.z));
  hi.w = f2bf(v3); lo.w = f2bf(v3 - b2f(hi.w));
  // packed tile-linear write for gemm2's A operand
  int mb = node >> 6, f = (node >> 4) & 3, l15 = node & 15;
  int ks = t >> 3, l4 = (t & 7) >> 1, half = t & 1;
  size_t base = (size_t)(mb * 32 + ks) * 8 * 512;
  size_t off = base + (size_t)f * 512 + (size_t)(l4 * 16 + l15) * 8 + half * 4;
  *(ushort4*)(o1pk + off) = hi;
  *(ushort4*)(o1pk + off + 4 * 512) = lo;
}

// ---- layer-2 aggregation (fp32 h2 gather), writes d_out -------------------

__global__ __launch_bounds__(256) void agg2_kernel(
    const float* __restrict__ h2, const float* __restrict__ a_s,
    const float* __restrict__ a_d, const int* __restrict__ offsets,
    const int* __restrict__ list, const float* __restrict__ b2,
    float* __restrict__ out, int n) {
  int w = threadIdx.x >> 6, lane = threadIdx.x & 63;
  int node = blockIdx.x * 4 + w;
  if (node >= n) return;
  int beg = offsets[node];
  int deg = offsets[node + 1] - beg;
  int tot = deg + 1;
  float ad = a_d[node];
  float mx = -3.4e38f;
  for (int i = lane; i < tot; i += 64) {
    int s = (i < deg) ? list[beg + i] : node;
    mx = fmaxf(mx, lrelu(a_s[s] + ad));
  }
  for (int o = 32; o; o >>= 1) mx = fmaxf(mx, __shfl_xor(mx, o));
  float sum = 0.f;
  for (int i = lane; i < tot; i += 64) {
    int s = (i < deg) ? list[beg + i] : node;
    sum += expf(lrelu(a_s[s] + ad) - mx);
  }
  for (int o = 32; o; o >>= 1) sum += __shfl_xor(sum, o);
  float den = sum + 1e-16f;
  float acc = 0.f;
  for (int i = 0; i < tot; ++i) {
    int s = (i < deg) ? list[beg + i] : node;
    float al = expf(lrelu(a_s[s] + ad) - mx) / den;
    acc += al * h2[(size_t)s * 64 + lane];
  }
  out[(size_t)node * 64 + lane] = acc + b2[lane];
}

// ---------------------------------------------------------------------------

extern "C" void kernel_launch(void* const* d_in, const int* in_sizes, int n_in,
                              void* d_out, int out_size, void* d_ws, size_t ws_size,
                              hipStream_t stream) {
  const float* x     = (const float*)d_in[0];
  const int*   ei    = (const int*)d_in[1];
  const float* W1    = (const float*)d_in[2];
  const float* asrc1 = (const float*)d_in[3];
  const float* adst1 = (const float*)d_in[4];
  const float* b1    = (const float*)d_in[5];
  const float* W2    = (const float*)d_in[6];
  const float* asrc2 = (const float*)d_in[7];
  const float* adst2 = (const float*)d_in[8];
  const float* b2    = (const float*)d_in[9];
  float* out = (float*)d_out;

  const int N = in_sizes[0] / 256;
  const int E = in_sizes[1] / 2;
  const int MB1 = (N + 63) / 64;
  const int Mpad = MB1 * 64;

  char* p = (char*)d_ws;
  auto bump = [&](size_t bytes) {
    char* r = p;
    p += (bytes + 255) & ~(size_t)255;
    return r;
  };
  int* counts  = (int*)bump((size_t)N * 4);
  int* offsets = (int*)bump((size_t)(N + 1) * 4);
  int* cursors = (int*)bump((size_t)N * 4);
  int* list    = (int*)bump((size_t)E * 4);
  unsigned short* xpk  = (unsigned short*)bump((size_t)Mpad * 512 * 2);   // hi+lo
  unsigned short* w1pk = (unsigned short*)bump((size_t)8 * 8 * 16 * 512 * 2);
  unsigned short* h1b  = (unsigned short*)bump((size_t)Mpad * 1024 * 2);
  float* as1           = (float*)bump((size_t)Mpad * 8 * 4);
  float* ad1           = (float*)bump((size_t)Mpad * 8 * 4);
  unsigned short* o1pk = (unsigned short*)bump((size_t)Mpad * 2048 * 2);  // hi+lo
  unsigned short* w2pk = (unsigned short*)bump((size_t)32 * 8 * 512 * 2);
  float* as2           = (float*)bump((size_t)Mpad * 4);
  float* ad2           = (float*)bump((size_t)Mpad * 4);
  // aliases (safe: single-stream ordering; last reader precedes first writer)
  float* h2p = (float*)h1b;   // 4*Mpad*64*4B = Mpad*1KB <= Mpad*2KB
  float* h2  = (float*)xpk;   // Mpad*64*4B = Mpad*256B <= Mpad*1KB

  // CSR
  hipMemsetAsync(counts, 0, (size_t)N * 4, stream);
  count_kernel<<<(E + 255) / 256, 256, 0, stream>>>(ei, counts, E);
  scan_kernel<<<1, 1024, 0, stream>>>(counts, offsets, cursors, N);
  fill_kernel<<<(E + 255) / 256, 256, 0, stream>>>(ei, cursors, list, E);

  // packing
  pack_x<<<dim3(MB1, 8), 256, 0, stream>>>(x, xpk, N);
  pack_w1<<<dim3(8, 8), 256, 0, stream>>>(W1, w1pk);
  pack_w2<<<32, 256, 0, stream>>>(W2, w2pk);

  // layer 1
  gemm1_att<<<dim3(MB1, 8), 256, 49152, stream>>>(xpk, w1pk, asrc1, adst1, h1b, as1, ad1);
  agg1_kernel<<<N, 256, 0, stream>>>(h1b, as1, ad1, offsets, list, b1, o1pk, N);

  // layer 2
  gemm2_splitk<<<dim3(MB1, 4), 256, 32768, stream>>>(o1pk, w2pk, h2p, Mpad);
  reduce_att2<<<(N + 3) / 4, 256, 0, stream>>>(h2p, asrc2, adst2, h2, as2, ad2, Mpad, N);
  agg2_kernel<<<(N + 3) / 4, 256, 0, stream>>>(h2, as2, ad2, offsets, list, b2, out, N);
}

// Round 4
// 192.556 us; speedup vs baseline: 1.7771x; 1.0827x over previous
//
#include <hip/hip_runtime.h>
#include <cmath>

// ---------------------------------------------------------------------------
// 2-layer GAT, N=10000, E=160000(+self loops), F_IN=256 -> [8x128 concat]=1024
// -> ELU -> [1x64]. Split-bf16 MFMA GEMMs (3-term), tile-linear packed
// operands (lane-contiguous global_load_lds), split-K GEMM2.
// Aggregations: single-pass, no-max softmax with deferred normalization.
// ---------------------------------------------------------------------------

typedef short bf16x8 __attribute__((ext_vector_type(8)));
typedef float f32x4 __attribute__((ext_vector_type(4)));
typedef unsigned short u16x8 __attribute__((ext_vector_type(8)));

__device__ __forceinline__ float lrelu(float x) { return x > 0.f ? x : 0.2f * x; }
__device__ __forceinline__ float b2f(unsigned short h) {
  return __uint_as_float(((unsigned)h) << 16);
}
__device__ __forceinline__ unsigned short f2bf(float f) {
  unsigned u = __float_as_uint(f);
  u += 0x7FFFu + ((u >> 16) & 1u);
  return (unsigned short)(u >> 16);
}

#define GLOAD_LDS16(gsrc, ldst)                                              \
  __builtin_amdgcn_global_load_lds(                                          \
      (const __attribute__((address_space(1))) unsigned int*)(gsrc),         \
      (__attribute__((address_space(3))) unsigned int*)(ldst), 16, 0, 0)

// ---- CSR build ------------------------------------------------------------

__global__ __launch_bounds__(256) void count_kernel(const int* __restrict__ ei,
                                                    int* __restrict__ counts, int E) {
  int e = blockIdx.x * 256 + threadIdx.x;
  if (e < E) atomicAdd(&counts[ei[E + e]], 1);
}

__global__ __launch_bounds__(1024) void scan_kernel(const int* __restrict__ counts,
                                                    int* __restrict__ offsets,
                                                    int* __restrict__ cursors, int n) {
  __shared__ int lds[1024];
  __shared__ int carry;
  if (threadIdx.x == 0) carry = 0;
  __syncthreads();
  for (int base = 0; base < n; base += 1024) {
    int i = base + (int)threadIdx.x;
    int v = (i < n) ? counts[i] : 0;
    lds[threadIdx.x] = v;
    __syncthreads();
    for (int off = 1; off < 1024; off <<= 1) {
      int t = (threadIdx.x >= (unsigned)off) ? lds[threadIdx.x - off] : 0;
      __syncthreads();
      lds[threadIdx.x] += t;
      __syncthreads();
    }
    int incl = lds[threadIdx.x];
    int c0 = carry;
    if (i < n) { int o = c0 + incl - v; offsets[i] = o; cursors[i] = o; }
    __syncthreads();
    if (threadIdx.x == 0) carry += lds[1023];
    __syncthreads();
  }
  if (threadIdx.x == 0) offsets[n] = carry;
}

__global__ __launch_bounds__(256) void fill_kernel(const int* __restrict__ ei,
                                                   int* __restrict__ cursors,
                                                   int* __restrict__ list, int E) {
  int e = blockIdx.x * 256 + threadIdx.x;
  if (e < E) {
    int d = ei[E + e];
    int pos = atomicAdd(&cursors[d], 1);
    list[pos] = ei[e];
  }
}

// ---- packing: tile-linear operand layout ----------------------------------
// Subtile = 16(rows) x 32(k) bf16 = 1024B, lane-linear: lane l supplies
// (row = l&15, kchunk = l>>4), 16B per lane.

__global__ __launch_bounds__(256) void pack_x(const float* __restrict__ x,
                                              unsigned short* __restrict__ xpk, int N) {
  int mb = blockIdx.x, ks = blockIdx.y;
  int t = threadIdx.x, l = t & 63, f = t >> 6;
  int row = mb * 64 + f * 16 + (l & 15);
  int kc = ks * 32 + (l >> 4) * 8;
  float v[8];
#pragma unroll
  for (int j = 0; j < 8; ++j) v[j] = 0.f;
  if (row < N) {
    const float* xr = x + (size_t)row * 256 + kc;
#pragma unroll
    for (int j = 0; j < 8; ++j) v[j] = xr[j];
  }
  u16x8 hi, lo;
#pragma unroll
  for (int j = 0; j < 8; ++j) {
    unsigned short h = f2bf(v[j]);
    hi[j] = h; lo[j] = f2bf(v[j] - b2f(h));
  }
  size_t base = (size_t)(mb * 8 + ks) * 8 * 512;
  *(u16x8*)(xpk + base + (size_t)f * 512 + l * 8) = hi;
  *(u16x8*)(xpk + base + (size_t)(4 + f) * 512 + l * 8) = lo;
}

__global__ __launch_bounds__(256) void pack_w1(const float* __restrict__ W,
                                               unsigned short* __restrict__ wpk) {
  int hb = blockIdx.x, ks = blockIdx.y;
  int t = threadIdx.x, l = t & 63, gq = t >> 6;
  for (int g = gq; g < 8; g += 4) {
    int n = hb * 128 + g * 16 + (l & 15);
    int k0 = ks * 32 + (l >> 4) * 8;
    u16x8 hi, lo;
#pragma unroll
    for (int j = 0; j < 8; ++j) {
      float v = W[(size_t)(k0 + j) * 1024 + n];
      unsigned short h = f2bf(v);
      hi[j] = h; lo[j] = f2bf(v - b2f(h));
    }
    size_t base = (size_t)(hb * 8 + ks) * 16 * 512;
    *(u16x8*)(wpk + base + (size_t)g * 512 + l * 8) = hi;
    *(u16x8*)(wpk + base + (size_t)(8 + g) * 512 + l * 8) = lo;
  }
}

__global__ __launch_bounds__(256) void pack_w2(const float* __restrict__ W,
                                               unsigned short* __restrict__ wpk) {
  int ks = blockIdx.x;
  int t = threadIdx.x, l = t & 63, g = t >> 6;
  int n = g * 16 + (l & 15);
  int k0 = ks * 32 + (l >> 4) * 8;
  u16x8 hi, lo;
#pragma unroll
  for (int j = 0; j < 8; ++j) {
    float v = W[(size_t)(k0 + j) * 64 + n];
    unsigned short h = f2bf(v);
    hi[j] = h; lo[j] = f2bf(v - b2f(h));
  }
  size_t base = (size_t)ks * 8 * 512;
  *(u16x8*)(wpk + base + (size_t)g * 512 + l * 8) = hi;
  *(u16x8*)(wpk + base + (size_t)(4 + g) * 512 + l * 8) = lo;
}

// ---- GEMM1 (split-bf16 MFMA) + fused att1 dots ----------------------------

__global__ __launch_bounds__(256) void gemm1_att(
    const unsigned short* __restrict__ xpk, const unsigned short* __restrict__ w1pk,
    const float* __restrict__ asrc, const float* __restrict__ adst,
    unsigned short* __restrict__ h1b, float* __restrict__ as1,
    float* __restrict__ ad1) {
  extern __shared__ char sm[];
  const int t = threadIdx.x, wid = t >> 6, lane = t & 63;
  const int mb = blockIdx.x, hb = blockIdx.y;
  const int m0 = mb * 64;
  const int l15 = lane & 15, l4 = lane >> 4;

  f32x4 acc[4][2] = {};

  auto stage = [&](int buf, int ks) {
    char* base0 = sm + buf * 24576;
    const unsigned short* ax = xpk + (size_t)(mb * 8 + ks) * 8 * 512 + lane * 8;
    for (int i = wid; i < 8; i += 4)
      GLOAD_LDS16(ax + i * 512, base0 + i * 1024);
    const unsigned short* bw = w1pk + (size_t)(hb * 8 + ks) * 16 * 512 + lane * 8;
    for (int i = wid; i < 16; i += 4)
      GLOAD_LDS16(bw + i * 512, base0 + 8192 + i * 1024);
  };

  stage(0, 0);
  __syncthreads();
  int buf = 0;
  for (int step = 0; step < 8; ++step) {
    if (step < 7) stage(buf ^ 1, step + 1);
    const char* b = sm + buf * 24576;
    bf16x8 ah[4], al[4], bh[2], bl[2];
#pragma unroll
    for (int mf = 0; mf < 4; ++mf) {
      ah[mf] = *(const bf16x8*)(b + mf * 1024 + lane * 16);
      al[mf] = *(const bf16x8*)(b + 4096 + mf * 1024 + lane * 16);
    }
#pragma unroll
    for (int nf = 0; nf < 2; ++nf) {
      int g = wid * 2 + nf;
      bh[nf] = *(const bf16x8*)(b + 8192 + g * 1024 + lane * 16);
      bl[nf] = *(const bf16x8*)(b + 16384 + g * 1024 + lane * 16);
    }
#pragma unroll
    for (int mf = 0; mf < 4; ++mf)
#pragma unroll
      for (int nf = 0; nf < 2; ++nf) {
        acc[mf][nf] = __builtin_amdgcn_mfma_f32_16x16x32_bf16(ah[mf], bh[nf], acc[mf][nf], 0, 0, 0);
        acc[mf][nf] = __builtin_amdgcn_mfma_f32_16x16x32_bf16(ah[mf], bl[nf], acc[mf][nf], 0, 0, 0);
        acc[mf][nf] = __builtin_amdgcn_mfma_f32_16x16x32_bf16(al[mf], bh[nf], acc[mf][nf], 0, 0, 0);
      }
    __syncthreads();
    buf ^= 1;
  }

  // epilogue: fused att dots (fp32 acc) + bf16 C-tile via LDS (coalesced out)
  float* parts_s = (float*)sm;                       // [64][4]
  float* parts_d = (float*)(sm + 1024);              // [64][4]
  unsigned short* ctile = (unsigned short*)(sm + 2048);  // [64][128]
  float as_c[2], ad_c[2];
#pragma unroll
  for (int nf = 0; nf < 2; ++nf) {
    int col = hb * 128 + wid * 32 + nf * 16 + l15;
    as_c[nf] = asrc[col];
    ad_c[nf] = adst[col];
  }
#pragma unroll
  for (int mf = 0; mf < 4; ++mf) {
    float ss[4] = {0.f, 0.f, 0.f, 0.f}, dd[4] = {0.f, 0.f, 0.f, 0.f};
#pragma unroll
    for (int nf = 0; nf < 2; ++nf)
#pragma unroll
      for (int r = 0; r < 4; ++r) {
        ss[r] += acc[mf][nf][r] * as_c[nf];
        dd[r] += acc[mf][nf][r] * ad_c[nf];
      }
#pragma unroll
    for (int r = 0; r < 4; ++r)
      for (int m = 1; m < 16; m <<= 1) {
        ss[r] += __shfl_xor(ss[r], m);
        dd[r] += __shfl_xor(dd[r], m);
      }
    if (l15 == 0) {
#pragma unroll
      for (int r = 0; r < 4; ++r) {
        int row = mf * 16 + l4 * 4 + r;
        parts_s[row * 4 + wid] = ss[r];
        parts_d[row * 4 + wid] = dd[r];
      }
    }
#pragma unroll
    for (int nf = 0; nf < 2; ++nf)
#pragma unroll
      for (int r = 0; r < 4; ++r) {
        int row = mf * 16 + l4 * 4 + r;
        int col = wid * 32 + nf * 16 + l15;
        ctile[row * 128 + col] = f2bf(acc[mf][nf][r]);
      }
  }
  __syncthreads();
  if (t < 64) {
    float s = parts_s[t * 4] + parts_s[t * 4 + 1] + parts_s[t * 4 + 2] + parts_s[t * 4 + 3];
    float d = parts_d[t * 4] + parts_d[t * 4 + 1] + parts_d[t * 4 + 2] + parts_d[t * 4 + 3];
    as1[(size_t)(m0 + t) * 8 + hb] = s;
    ad1[(size_t)(m0 + t) * 8 + hb] = d;
  }
#pragma unroll
  for (int rep = 0; rep < 4; ++rep) {
    int e = rep * 2048 + t * 8;
    int row = e >> 7, col = e & 127;
    bf16x8 v = *(const bf16x8*)(ctile + e);
    *(bf16x8*)(h1b + (size_t)(m0 + row) * 1024 + hb * 128 + col) = v;
  }
}

// ---- GEMM2 (split-bf16 MFMA, split-K=4) -----------------------------------

__global__ __launch_bounds__(256) void gemm2_splitk(
    const unsigned short* __restrict__ o1pk, const unsigned short* __restrict__ w2pk,
    float* __restrict__ h2p, int Mpad) {
  extern __shared__ char sm[];
  const int t = threadIdx.x, wid = t >> 6, lane = t & 63;
  const int wr = wid >> 1, wc = wid & 1;
  const int mb = blockIdx.x, sk = blockIdx.y;
  const int m0 = mb * 64;
  const int l15 = lane & 15, l4 = lane >> 4;

  f32x4 acc[2][2] = {};

  auto stage = [&](int buf, int ks) {
    char* base0 = sm + buf * 16384;
    const unsigned short* ax = o1pk + (size_t)(mb * 32 + ks) * 8 * 512 + lane * 8;
    for (int i = wid; i < 8; i += 4)
      GLOAD_LDS16(ax + i * 512, base0 + i * 1024);
    const unsigned short* bw = w2pk + (size_t)ks * 8 * 512 + lane * 8;
    for (int i = wid; i < 8; i += 4)
      GLOAD_LDS16(bw + i * 512, base0 + 8192 + i * 1024);
  };

  stage(0, sk * 8);
  __syncthreads();
  int buf = 0;
  for (int step = 0; step < 8; ++step) {
    if (step < 7) stage(buf ^ 1, sk * 8 + step + 1);
    const char* b = sm + buf * 16384;
    bf16x8 ah[2], al[2], bh[2], bl[2];
#pragma unroll
    for (int mf = 0; mf < 2; ++mf) {
      int f = wr * 2 + mf;
      ah[mf] = *(const bf16x8*)(b + f * 1024 + lane * 16);
      al[mf] = *(const bf16x8*)(b + 4096 + f * 1024 + lane * 16);
    }
#pragma unroll
    for (int nf = 0; nf < 2; ++nf) {
      int g = wc * 2 + nf;
      bh[nf] = *(const bf16x8*)(b + 8192 + g * 1024 + lane * 16);
      bl[nf] = *(const bf16x8*)(b + 12288 + g * 1024 + lane * 16);
    }
#pragma unroll
    for (int mf = 0; mf < 2; ++mf)
#pragma unroll
      for (int nf = 0; nf < 2; ++nf) {
        acc[mf][nf] = __builtin_amdgcn_mfma_f32_16x16x32_bf16(ah[mf], bh[nf], acc[mf][nf], 0, 0, 0);
        acc[mf][nf] = __builtin_amdgcn_mfma_f32_16x16x32_bf16(ah[mf], bl[nf], acc[mf][nf], 0, 0, 0);
        acc[mf][nf] = __builtin_amdgcn_mfma_f32_16x16x32_bf16(al[mf], bh[nf], acc[mf][nf], 0, 0, 0);
      }
    __syncthreads();
    buf ^= 1;
  }

#pragma unroll
  for (int mf = 0; mf < 2; ++mf)
#pragma unroll
    for (int nf = 0; nf < 2; ++nf)
#pragma unroll
      for (int r = 0; r < 4; ++r) {
        int row = wr * 32 + mf * 16 + l4 * 4 + r;
        int col = wc * 32 + nf * 16 + l15;
        h2p[((size_t)sk * Mpad + m0 + row) * 64 + col] = acc[mf][nf][r];
      }
}

// ---- reduce split-K partials + att2 dots ----------------------------------

__global__ __launch_bounds__(256) void reduce_att2(
    const float* __restrict__ h2p, const float* __restrict__ asrc,
    const float* __restrict__ adst, float* __restrict__ h2,
    float* __restrict__ as2, float* __restrict__ ad2, int Mpad, int n) {
  int w = threadIdx.x >> 6, lane = threadIdx.x & 63;
  int row = blockIdx.x * 4 + w;
  if (row >= n) return;
  float s = 0.f;
#pragma unroll
  for (int sk = 0; sk < 4; ++sk) s += h2p[((size_t)sk * Mpad + row) * 64 + lane];
  h2[(size_t)row * 64 + lane] = s;
  float ds = s * asrc[lane], dd = s * adst[lane];
  for (int o = 32; o; o >>= 1) { ds += __shfl_xor(ds, o); dd += __shfl_xor(dd, o); }
  if (lane == 0) { as2[row] = ds; ad2[row] = dd; }
}

// ---- layer-1 aggregation: single-pass no-max softmax, deferred normalize --
// One block per node. e computed once per (src,head) (coalesced a_s reads),
// gather 16B/lane (2 src rows per iteration), normalize in epilogue.

__global__ __launch_bounds__(256) void agg1_kernel(
    const unsigned short* __restrict__ h1b, const float* __restrict__ a_s,
    const float* __restrict__ a_d, const int* __restrict__ offsets,
    const int* __restrict__ list, const float* __restrict__ b1,
    unsigned short* __restrict__ o1pk, int n) {
  int node = blockIdx.x;
  int t = threadIdx.x;
  int beg = offsets[node];
  int deg = offsets[node + 1] - beg;
  int tot = deg + 1;  // + self loop

  __shared__ int src_s[64];
  __shared__ float e_s[64][8];
  __shared__ float dpart[256];
  __shared__ float den_s[8];
  __shared__ float red[128 * 9];  // padded stride 9 vs bank conflicts

  const int jj = t >> 3, hh = t & 7;          // e-compute role
  const float ad_h = a_d[(size_t)node * 8 + hh];
  const int joff = t >> 7;                     // gather role: row parity
  const int coff = (t & 127) * 8;              // 8 channels per thread
  const int hsel = (t & 127) >> 4;             // head of those channels

  float den_part = 0.f;
  float accv[8] = {};

  for (int c0 = 0; c0 < tot; c0 += 64) {
    int cnt = min(64, tot - c0);
    if (t < 64) { int i = c0 + t; src_s[t] = (i < deg) ? list[beg + i] : node; }
    __syncthreads();
    {
      float e0 = 0.f, e1 = 0.f;
      if (jj < cnt) e0 = __expf(lrelu(a_s[(size_t)src_s[jj] * 8 + hh] + ad_h));
      if (jj + 32 < cnt) e1 = __expf(lrelu(a_s[(size_t)src_s[jj + 32] * 8 + hh] + ad_h));
      e_s[jj][hh] = e0;
      e_s[jj + 32][hh] = e1;
      den_part += e0 + e1;
    }
    __syncthreads();
    int cntp = (cnt + 1) & ~1;
    for (int j = 0; j < cntp; j += 2) {
      int jr = j + joff;
      const bf16x8 v = *(const bf16x8*)(h1b + (size_t)src_s[jr] * 1024 + coff);
      float w = e_s[jr][hsel];
#pragma unroll
      for (int k = 0; k < 8; ++k)
        accv[k] += w * b2f((unsigned short)v[k]);
    }
    __syncthreads();
  }

  // denominator reduce
  dpart[t] = den_part;
  __syncthreads();
  if (t < 8) {
    float s = 0.f;
    for (int j = 0; j < 32; ++j) s += dpart[j * 8 + t];
    den_s[t] = s + 1e-16f;
  }
  // pair-reduce accumulators (t and t+128 share channels, differ in row parity)
  if (t >= 128) {
#pragma unroll
    for (int k = 0; k < 8; ++k) red[(t - 128) * 9 + k] = accv[k];
  }
  __syncthreads();
  if (t < 128) {
    float inv = 1.f / den_s[hsel];
    float vv[8];
#pragma unroll
    for (int k = 0; k < 8; ++k) {
      float v = (accv[k] + red[t * 9 + k]) * inv + b1[coff + k];
      vv[k] = v > 0.f ? v : expm1f(v);
    }
    u16x8 hi, lo;
#pragma unroll
    for (int k = 0; k < 8; ++k) {
      unsigned short h = f2bf(vv[k]);
      hi[k] = h; lo[k] = f2bf(vv[k] - b2f(h));
    }
    // packed tile-linear write for gemm2's A operand (c = t*8 .. t*8+7)
    int mb = node >> 6, f = (node >> 4) & 3, l15 = node & 15;
    int ks = t >> 2, kc = t & 3;
    size_t base = (size_t)(mb * 32 + ks) * 8 * 512;
    size_t off = base + (size_t)f * 512 + (size_t)(kc * 16 + l15) * 8;
    *(u16x8*)(o1pk + off) = hi;
    *(u16x8*)(o1pk + off + 4 * 512) = lo;
  }
}

// ---- layer-2 aggregation: single-pass no-max, shfl-broadcast, float4 ------

__global__ __launch_bounds__(256) void agg2_kernel(
    const float* __restrict__ h2, const float* __restrict__ a_s,
    const float* __restrict__ a_d, const int* __restrict__ offsets,
    const int* __restrict__ list, const float* __restrict__ b2,
    float* __restrict__ out, int n) {
  int w = threadIdx.x >> 6, lane = threadIdx.x & 63;
  int node = blockIdx.x * 4 + w;
  if (node >= n) return;
  int beg = offsets[node];
  int deg = offsets[node + 1] - beg;
  int tot = deg + 1;
  float ad = a_d[node];
  const int cb = (lane & 15) * 4;  // 4 channels per lane
  const int jo = lane >> 4;        // row-in-quad

  float4 acc = make_float4(0.f, 0.f, 0.f, 0.f);
  float den = 0.f;
  for (int c0 = 0; c0 < tot; c0 += 64) {
    int cnt = min(64, tot - c0);
    int i = c0 + lane;
    int s_mine = (i < deg) ? list[beg + i] : node;
    float e_mine = (i < tot) ? __expf(lrelu(a_s[s_mine] + ad)) : 0.f;
    den += e_mine;
    int cntp = (cnt + 3) & ~3;
    for (int j = 0; j < cntp; j += 4) {
      int jr = j + jo;
      float e = __shfl(e_mine, jr);
      int s = __shfl(s_mine, jr);
      float4 v = *(const float4*)&h2[(size_t)s * 64 + cb];
      acc.x += e * v.x; acc.y += e * v.y; acc.z += e * v.z; acc.w += e * v.w;
    }
  }
  for (int o = 32; o; o >>= 1) den += __shfl_xor(den, o);
  acc.x += __shfl_xor(acc.x, 16); acc.y += __shfl_xor(acc.y, 16);
  acc.z += __shfl_xor(acc.z, 16); acc.w += __shfl_xor(acc.w, 16);
  acc.x += __shfl_xor(acc.x, 32); acc.y += __shfl_xor(acc.y, 32);
  acc.z += __shfl_xor(acc.z, 32); acc.w += __shfl_xor(acc.w, 32);
  if (jo == 0) {
    float inv = 1.f / (den + 1e-16f);
    float4 r;
    r.x = acc.x * inv + b2[cb];
    r.y = acc.y * inv + b2[cb + 1];
    r.z = acc.z * inv + b2[cb + 2];
    r.w = acc.w * inv + b2[cb + 3];
    *(float4*)&out[(size_t)node * 64 + cb] = r;
  }
}

// ---------------------------------------------------------------------------

extern "C" void kernel_launch(void* const* d_in, const int* in_sizes, int n_in,
                              void* d_out, int out_size, void* d_ws, size_t ws_size,
                              hipStream_t stream) {
  const float* x     = (const float*)d_in[0];
  const int*   ei    = (const int*)d_in[1];
  const float* W1    = (const float*)d_in[2];
  const float* asrc1 = (const float*)d_in[3];
  const float* adst1 = (const float*)d_in[4];
  const float* b1    = (const float*)d_in[5];
  const float* W2    = (const float*)d_in[6];
  const float* asrc2 = (const float*)d_in[7];
  const float* adst2 = (const float*)d_in[8];
  const float* b2    = (const float*)d_in[9];
  float* out = (float*)d_out;

  const int N = in_sizes[0] / 256;
  const int E = in_sizes[1] / 2;
  const int MB1 = (N + 63) / 64;
  const int Mpad = MB1 * 64;

  char* p = (char*)d_ws;
  auto bump = [&](size_t bytes) {
    char* r = p;
    p += (bytes + 255) & ~(size_t)255;
    return r;
  };
  int* counts  = (int*)bump((size_t)N * 4);
  int* offsets = (int*)bump((size_t)(N + 1) * 4);
  int* cursors = (int*)bump((size_t)N * 4);
  int* list    = (int*)bump((size_t)E * 4);
  unsigned short* xpk  = (unsigned short*)bump((size_t)Mpad * 512 * 2);   // hi+lo
  unsigned short* w1pk = (unsigned short*)bump((size_t)8 * 8 * 16 * 512 * 2);
  unsigned short* h1b  = (unsigned short*)bump((size_t)Mpad * 1024 * 2);
  float* as1           = (float*)bump((size_t)Mpad * 8 * 4);
  float* ad1           = (float*)bump((size_t)Mpad * 8 * 4);
  unsigned short* o1pk = (unsigned short*)bump((size_t)Mpad * 2048 * 2);  // hi+lo
  unsigned short* w2pk = (unsigned short*)bump((size_t)32 * 8 * 512 * 2);
  float* as2           = (float*)bump((size_t)Mpad * 4);
  float* ad2           = (float*)bump((size_t)Mpad * 4);
  // aliases (safe: single-stream ordering; last reader precedes first writer)
  float* h2p = (float*)h1b;   // 4*Mpad*64*4B = Mpad*1KB <= Mpad*2KB
  float* h2  = (float*)xpk;   // Mpad*64*4B = Mpad*256B <= Mpad*1KB

  // CSR
  hipMemsetAsync(counts, 0, (size_t)N * 4, stream);
  count_kernel<<<(E + 255) / 256, 256, 0, stream>>>(ei, counts, E);
  scan_kernel<<<1, 1024, 0, stream>>>(counts, offsets, cursors, N);
  fill_kernel<<<(E + 255) / 256, 256, 0, stream>>>(ei, cursors, list, E);

  // packing
  pack_x<<<dim3(MB1, 8), 256, 0, stream>>>(x, xpk, N);
  pack_w1<<<dim3(8, 8), 256, 0, stream>>>(W1, w1pk);
  pack_w2<<<32, 256, 0, stream>>>(W2, w2pk);

  // layer 1
  gemm1_att<<<dim3(MB1, 8), 256, 49152, stream>>>(xpk, w1pk, asrc1, adst1, h1b, as1, ad1);
  agg1_kernel<<<N, 256, 0, stream>>>(h1b, as1, ad1, offsets, list, b1, o1pk, N);

  // layer 2
  gemm2_splitk<<<dim3(MB1, 4), 256, 32768, stream>>>(o1pk, w2pk, h2p, Mpad);
  reduce_att2<<<(N + 3) / 4, 256, 0, stream>>>(h2p, asrc2, adst2, h2, as2, ad2, Mpad, N);
  agg2_kernel<<<(N + 3) / 4, 256, 0, stream>>>(h2, as2, ad2, offsets, list, b2, out, N);
}